// Round 4
// baseline (160.512 us; speedup 1.0000x reference)
//
#include <hip/hip_runtime.h>
#include <math.h>

#define BB 8
#define HH 64
#define WW 64
#define CINC 32
#define COUTC 64
#define KK 8
#define VSN 12
#define HIDDEN 128
#define ADIN 34

// transpose x (B,CIN,H,W) -> xf (B,H*W,CIN)
__global__ __launch_bounds__(256) void transpose_x(const float* __restrict__ x,
                                                   float* __restrict__ xf) {
    int tid = blockIdx.x * 256 + threadIdx.x;   // output-linear
    int c   = tid & 31;
    int pos = (tid >> 5) & 4095;
    int b   = tid >> 17;
    xf[tid] = x[((b * CINC + c) << 12) + pos];
}

__global__ __launch_bounds__(256) void fused_kernel(
    const float* __restrict__ x,     // (B,CIN,H,W)
    const float* __restrict__ xf,    // (B,H*W,CIN) or unused
    const float* __restrict__ W1,    // (34,128)
    const float* __restrict__ b1,    // (128)
    const float* __restrict__ W2,    // (128,24)
    const float* __restrict__ b2,    // (24)
    const float* __restrict__ Wu,    // (256,64)
    const float* __restrict__ bu,    // (64)
    const int*   __restrict__ gidx,  // (B,H,W,K,4,2)
    const int*   __restrict__ loff,  // (B,H,W,K,4,2)
    float*       __restrict__ out,   // (B,COUT,H,W)
    int use_xf)
{
    __shared__ float sInp[4][ADIN];
    __shared__ float sH[4][HIDDEN];
    __shared__ float sP[4][24];
    __shared__ int   sFlat[4][KK][VSN];
    __shared__ float sProp[4][KK][VSN];
    __shared__ float sInv[4][KK];
    __shared__ float sFeat[4][KK * CINC];

    const int w   = threadIdx.x >> 6;   // wave id 0..3 (one pixel each)
    const int wl  = threadIdx.x & 63;   // lane
    const int pix = blockIdx.x * 4 + w; // linear pixel
    const int b   = pix >> 12;
    const int rem = pix & 4095;         // i*64 + j
    const int i   = rem >> 6;
    const int j   = rem & 63;

    // ---- phase 1: build MLP input [x(32), i/63, j/63] ----
    if (wl < CINC) {
        float v = use_xf ? xf[(((b << 12) + rem) << 5) + wl]
                         : x[((b * CINC + wl) << 12) + rem];
        sInp[w][wl] = v;
    } else if (wl == 32) {
        sInp[w][32] = (float)i / 63.0f;
    } else if (wl == 33) {
        sInp[w][33] = (float)j / 63.0f;
    }
    __syncthreads();

    // ---- phase 2: hidden = relu(inp @ W1 + b1), 2 units per lane ----
    {
        float acc0 = b1[wl];
        float acc1 = b1[wl + 64];
        #pragma unroll
        for (int a = 0; a < ADIN; ++a) {
            float iv = sInp[w][a];
            acc0 = fmaf(iv, W1[a * HIDDEN + wl],      acc0);
            acc1 = fmaf(iv, W1[a * HIDDEN + wl + 64], acc1);
        }
        sH[w][wl]      = fmaxf(acc0, 0.0f);
        sH[w][wl + 64] = fmaxf(acc1, 0.0f);
    }
    __syncthreads();

    // ---- phase 3: params = hidden @ W2 + b2 (24 outputs) ----
    if (wl < 24) {
        float acc = b2[wl];
        #pragma unroll 8
        for (int u = 0; u < HIDDEN; ++u)
            acc = fmaf(sH[w][u], W2[u * 24 + wl], acc);
        sP[w][wl] = acc;
    }
    __syncthreads();

    // ---- phase 4: gaussian params, sample indices, props ----
    const int k   = wl >> 3;   // gaussian id
    const int sub = wl & 7;

    float mr0 = sP[w][2 * k];
    float mr1 = sP[w][2 * k + 1];
    float sr  = sP[w][16 + k];

    float mid0 = ((float)i / 63.0f) * 63.0f;
    float mid1 = ((float)j / 63.0f) * 63.0f;
    float m0 = fmodf(mid0 + mr0, 63.0f); if (m0 < 0.0f) m0 += 63.0f;
    float m1 = fmodf(mid1 + mr1, 63.0f); if (m1 < 0.0f) m1 += 63.0f;

    float sx  = sr + 2.0f;                                  // SIGMA_BOOST
    float spv = fmaxf(sx, 0.0f) + log1pf(expf(-fabsf(sx))); // softplus
    float sig = ((spv + 0.05f) * 63.0f) * 0.05f;            // (sp+MIN)*hw1*SCALE

    int fl0 = (int)floorf(m0);
    int fl1 = (int)floorf(m1);

    const int gl_base = (pix * KK + k) << 3;  // base into gidx/loff (k-slice)

    #pragma unroll
    for (int t = 0; t < 2; ++t) {
        if (t == 1 && sub >= 4) break;
        int v = (t == 0) ? sub : 8 + sub;
        int i0, j0;
        if (v < 4) {
            i0 = (fl0 + (v >> 1)) & 63;
            j0 = (fl1 + (v & 1)) & 63;
        } else if (v < 8) {
            int g = (v - 4) << 1;
            i0 = gidx[gl_base + g];
            j0 = gidx[gl_base + g + 1];
        } else {
            int r = (v - 8) << 1;
            i0 = (fl0 + loff[gl_base + r]     - 8 + 64) & 63;
            j0 = (fl1 + loff[gl_base + r + 1] - 8 + 64) & 63;
        }
        float z0 = ((float)i0 - m0) / sig;
        float z1 = ((float)j0 - m1) / sig;
        float pr = expf(-0.5f * (z0 * z0 + z1 * z1));
        sFlat[w][k][v] = i0 * 64 + j0;
        sProp[w][k][v] = pr;
    }
    __syncthreads();

    // dup-zero: zero prop if any earlier v' (same k) has same flat index
    #pragma unroll
    for (int t = 0; t < 2; ++t) {
        if (t == 1 && sub >= 4) break;
        int v = (t == 0) ? sub : 8 + sub;
        int f = sFlat[w][k][v];
        bool dup = false;
        for (int v2 = 0; v2 < v; ++v2)
            dup |= (sFlat[w][k][v2] == f);
        if (dup) sProp[w][k][v] = 0.0f;
    }
    __syncthreads();

    if (sub == 0) {
        float s = 0.0f;
        #pragma unroll
        for (int v = 0; v < VSN; ++v) s += sProp[w][k][v];
        sInv[w][k] = 1.0f / s;
    }
    __syncthreads();

    // ---- phase 5: gather + weighted sum -> feat[k*32 + c] ----
    {
        const int c4 = sub << 2;
        float a0 = 0.f, a1 = 0.f, a2 = 0.f, a3 = 0.f;
        float isum = sInv[w][k];
        #pragma unroll
        for (int v = 0; v < VSN; ++v) {
            float wt = sProp[w][k][v] * isum;
            int p = sFlat[w][k][v];
            if (use_xf) {
                const float4 xv = *(const float4*)&xf[(((b << 12) + p) << 5) + c4];
                a0 = fmaf(wt, xv.x, a0);
                a1 = fmaf(wt, xv.y, a1);
                a2 = fmaf(wt, xv.z, a2);
                a3 = fmaf(wt, xv.w, a3);
            } else {
                const float* xb = x + ((b * CINC + c4) << 12) + p;
                a0 = fmaf(wt, xb[0],        a0);
                a1 = fmaf(wt, xb[1 << 12],  a1);
                a2 = fmaf(wt, xb[2 << 12],  a2);
                a3 = fmaf(wt, xb[3 << 12],  a3);
            }
        }
        int fb = k * CINC + c4;
        sFeat[w][fb]     = a0;
        sFeat[w][fb + 1] = a1;
        sFeat[w][fb + 2] = a2;
        sFeat[w][fb + 3] = a3;
    }
    __syncthreads();

    // ---- phase 6: out[o] = feat(256) . Wu[:,o] + bu[o] ----
    {
        const int o = wl;
        float acc = bu[o];
        #pragma unroll 8
        for (int jj = 0; jj < 256; ++jj)
            acc = fmaf(sFeat[w][jj], Wu[(jj << 6) + o], acc);
        out[(((b << 6) + o) << 12) + rem] = acc;
    }
}

extern "C" void kernel_launch(void* const* d_in, const int* in_sizes, int n_in,
                              void* d_out, int out_size, void* d_ws, size_t ws_size,
                              hipStream_t stream) {
    const float* x    = (const float*)d_in[0];
    const float* W1   = (const float*)d_in[1];
    const float* b1   = (const float*)d_in[2];
    const float* W2   = (const float*)d_in[3];
    const float* b2   = (const float*)d_in[4];
    const float* Wu   = (const float*)d_in[5];
    const float* bu   = (const float*)d_in[6];
    const int*   gidx = (const int*)d_in[7];
    const int*   loff = (const int*)d_in[8];
    float* outp = (float*)d_out;

    const size_t xf_bytes = (size_t)BB * HH * WW * CINC * 4;  // 4 MiB
    int use_xf = (ws_size >= xf_bytes) ? 1 : 0;
    float* xf = (float*)d_ws;

    if (use_xf) {
        transpose_x<<<(BB * CINC * HH * WW) / 256, 256, 0, stream>>>(x, xf);
    }
    // 32768 pixels, 4 per block
    fused_kernel<<<(BB * HH * WW) / 4, 256, 0, stream>>>(
        x, xf, W1, b1, W2, b2, Wu, bu, gidx, loff, outp, use_xf);
}

// Round 5
// 109.779 us; speedup vs baseline: 1.4621x; 1.4621x over previous
//
#include <hip/hip_runtime.h>
#include <hip/hip_bf16.h>
#include <math.h>

#define BB 8
#define HH 64
#define WW 64
#define CINC 32
#define COUTC 64
#define KK 8
#define VSN 12
#define HIDDEN 128
#define ADIN 34
#define PXB 16           // pixels per block
#define FPAD 260         // padded sFeat row stride (floats): 256+4 kills bank conflicts

typedef short short8 __attribute__((ext_vector_type(8)));
typedef float f32x4 __attribute__((ext_vector_type(4)));

__device__ __forceinline__ short f2bfs(float f) {
    __hip_bfloat16 h = __float2bfloat16(f);   // RNE
    return __builtin_bit_cast(short, h);
}
__device__ __forceinline__ float bfs2f(short s) {
    return __bfloat162float(__builtin_bit_cast(__hip_bfloat16, s));
}

// transpose x (B,CIN,H,W) -> xf (B,H*W,CIN)
__global__ __launch_bounds__(256) void transpose_x(const float* __restrict__ x,
                                                   float* __restrict__ xf) {
    int tid = blockIdx.x * 256 + threadIdx.x;
    int c   = tid & 31;
    int pos = (tid >> 5) & 4095;
    int b   = tid >> 17;
    xf[tid] = x[((b * CINC + c) << 12) + pos];
}

// split Wu (256,64) f32 into bf16 hi/lo, pre-swizzled into MFMA B-fragment order:
// slot base = ((s*4+kg)*64 + c)*16 shorts, j=0..7 hi, 8..15 lo,
// where row r = s*32 + kg*8 + j.
__global__ __launch_bounds__(256) void pack_wu(const float* __restrict__ Wu,
                                               short* __restrict__ bs) {
    int tid = blockIdx.x * 256 + threadIdx.x;   // 16384
    int r = tid >> 6, c = tid & 63;
    float f  = Wu[tid];
    short hi = f2bfs(f);
    short lo = f2bfs(f - bfs2f(hi));
    int s = r >> 5, r5 = r & 31, kg = r5 >> 3, j = r5 & 7;
    int base = ((((s << 2) + kg) << 6) | c) << 4;
    bs[base + j]     = hi;
    bs[base + 8 + j] = lo;
}

__global__ __launch_bounds__(256, 2) void fused2(
    const float* __restrict__ x,   const float* __restrict__ xf,
    const float* __restrict__ W1,  const float* __restrict__ b1,
    const float* __restrict__ W2,  const float* __restrict__ b2,
    const float* __restrict__ Wu,  const short* __restrict__ bs,
    const float* __restrict__ bu,
    const int*  __restrict__ gidx, const int* __restrict__ loff,
    float*      __restrict__ out,  int use_ws)
{
    // LDS overlay:
    //   [0,16640)   : sFeat f32[16][260]   (phase 5/6)  -- overlays sInp/sH/sP
    //   [0,2176)    : sInp  f32[16][34]    (phases 1-2)
    //   [2176,10368): sH    f32[16][128]   (phases 2-3)
    //   [10368,11904): sP   f32[16][24]    (phases 3-4)
    //   [16640,22784): sFlat i32[16][8][12]
    //   [22784,28928): sProp f32[16][8][12]
    //   [28928,29440): sInv  f32[16][8]
    __shared__ __align__(16) char lds[29440];
    float* sFeat = (float*)lds;
    float* sInp  = (float*)lds;
    float* sH    = (float*)(lds + 2176);
    float* sP    = (float*)(lds + 10368);
    int*   sFlat = (int*)  (lds + 16640);
    float* sProp = (float*)(lds + 22784);
    float* sInv  = (float*)(lds + 28928);

    const int t    = threadIdx.x;
    const int w    = t >> 6;        // wave 0..3
    const int wl   = t & 63;
    const int pix0 = blockIdx.x * PXB;
    const int b    = pix0 >> 12;
    const int rem0 = pix0 & 4095;   // 16 consecutive pixels, same b
    const int w4   = w << 2;        // first local pixel of this wave

    // ---- P1: cooperative input staging ----
    {
        int c = t & 31;
        #pragma unroll
        for (int it = 0; it < 2; ++it) {
            int lp  = (t >> 5) + (it << 3);
            int rem = rem0 + lp;
            sInp[lp * ADIN + c] = use_ws ? xf[(((b << 12) + rem) << 5) + c]
                                         : x[(((b << 5) + c) << 12) + rem];
        }
        if (t < PXB) {
            int rem = rem0 + t;
            sInp[t * ADIN + 32] = (float)(rem >> 6) / 63.0f;
            sInp[t * ADIN + 33] = (float)(rem & 63) / 63.0f;
        }
    }
    __syncthreads();

    // ---- P2: hidden = relu(inp @ W1 + b1), 4 pixels/wave, weights loaded once ----
    {
        float h0[4], h1[4];
        #pragma unroll
        for (int q = 0; q < 4; ++q) { h0[q] = b1[wl]; h1[q] = b1[wl + 64]; }
        #pragma unroll 2
        for (int a = 0; a < ADIN; ++a) {
            float wa = W1[a * HIDDEN + wl];
            float wb = W1[a * HIDDEN + wl + 64];
            #pragma unroll
            for (int q = 0; q < 4; ++q) {
                float iv = sInp[(w4 + q) * ADIN + a];
                h0[q] = fmaf(iv, wa, h0[q]);
                h1[q] = fmaf(iv, wb, h1[q]);
            }
        }
        #pragma unroll
        for (int q = 0; q < 4; ++q) {
            sH[(w4 + q) * HIDDEN + wl]      = fmaxf(h0[q], 0.f);
            sH[(w4 + q) * HIDDEN + wl + 64] = fmaxf(h1[q], 0.f);
        }
    }
    // sH rows are wave-private: no barrier needed (in-wave LDS ordering)

    // ---- P3: params = hidden @ W2 + b2; 48 lanes cover 2 pixels/pass ----
    #pragma unroll
    for (int qq = 0; qq < 2; ++qq) {
        if (wl < 48) {
            int hi = (wl >= 24) ? 1 : 0;
            int q  = (qq << 1) + hi;
            int o  = wl - (hi ? 24 : 0);
            int lp = w4 + q;
            float acc = b2[o];
            #pragma unroll 4
            for (int u = 0; u < HIDDEN; ++u)
                acc = fmaf(sH[lp * HIDDEN + u], W2[u * 24 + o], acc);
            sP[lp * 24 + o] = acc;
        }
    }
    // sP rows wave-private: no barrier

    const int k   = wl >> 3;
    const int sub = wl & 7;

    // ---- P4 (+dup+norm): per wave, 4 pixels sequentially; all wave-local LDS ----
    #pragma unroll 1
    for (int q = 0; q < 4; ++q) {
        int lp  = w4 + q;
        int rem = rem0 + lp;
        int pix = pix0 + lp;
        int i   = rem >> 6, j = rem & 63;

        float mr0 = sP[lp * 24 + 2 * k];
        float mr1 = sP[lp * 24 + 2 * k + 1];
        float sr  = sP[lp * 24 + 16 + k];

        float mid0 = ((float)i / 63.0f) * 63.0f;
        float mid1 = ((float)j / 63.0f) * 63.0f;
        float m0 = fmodf(mid0 + mr0, 63.0f); if (m0 < 0.f) m0 += 63.0f;
        float m1 = fmodf(mid1 + mr1, 63.0f); if (m1 < 0.f) m1 += 63.0f;

        float sx  = sr + 2.0f;                                   // SIGMA_BOOST
        float spv = fmaxf(sx, 0.f) + log1pf(expf(-fabsf(sx)));   // softplus
        float sig = ((spv + 0.05f) * 63.0f) * 0.05f;

        int fl0 = (int)floorf(m0);
        int fl1 = (int)floorf(m1);
        const int glb = (pix * KK + k) << 3;
        const int fpb = (lp * KK + k) * VSN;

        #pragma unroll
        for (int tt = 0; tt < 2; ++tt) {
            if (tt == 1 && sub >= 4) break;
            int v = (tt == 0) ? sub : 8 + sub;
            int i0, j0;
            if (v < 4) {
                i0 = (fl0 + (v >> 1)) & 63;
                j0 = (fl1 + (v & 1)) & 63;
            } else if (v < 8) {
                int g = (v - 4) << 1;
                i0 = gidx[glb + g];
                j0 = gidx[glb + g + 1];
            } else {
                int r = (v - 8) << 1;
                i0 = (fl0 + loff[glb + r]     - 8 + 64) & 63;
                j0 = (fl1 + loff[glb + r + 1] - 8 + 64) & 63;
            }
            float z0 = ((float)i0 - m0) / sig;
            float z1 = ((float)j0 - m1) / sig;
            sFlat[fpb + v] = i0 * 64 + j0;
            sProp[fpb + v] = expf(-0.5f * (z0 * z0 + z1 * z1));
        }
        // dup-zero (reads other lanes of same wave; in-wave LDS order suffices)
        #pragma unroll
        for (int tt = 0; tt < 2; ++tt) {
            if (tt == 1 && sub >= 4) break;
            int v = (tt == 0) ? sub : 8 + sub;
            int f = sFlat[fpb + v];
            bool dup = false;
            for (int v2 = 0; v2 < v; ++v2)
                dup |= (sFlat[fpb + v2] == f);
            if (dup) sProp[fpb + v] = 0.0f;
        }
        if (sub == 0) {
            float s = 0.0f;
            #pragma unroll
            for (int v = 0; v < VSN; ++v) s += sProp[fpb + v];
            sInv[lp * KK + k] = 1.0f / s;
        }
    }
    __syncthreads();   // overlay guard: all sInp/sH/sP reads done before sFeat writes

    // ---- P5: gather + weighted sum -> sFeat[lp][k*32+c] ----
    #pragma unroll 1
    for (int q = 0; q < 4; ++q) {
        int lp  = w4 + q;
        const int fpb = (lp * KK + k) * VSN;
        float isum = sInv[lp * KK + k];
        int c4 = sub << 2;
        float a0 = 0.f, a1 = 0.f, a2 = 0.f, a3 = 0.f;
        #pragma unroll
        for (int v = 0; v < VSN; ++v) {
            float wt = sProp[fpb + v] * isum;
            int p = sFlat[fpb + v];
            if (use_ws) {
                const float4 xv = *(const float4*)&xf[(((b << 12) + p) << 5) + c4];
                a0 = fmaf(wt, xv.x, a0);
                a1 = fmaf(wt, xv.y, a1);
                a2 = fmaf(wt, xv.z, a2);
                a3 = fmaf(wt, xv.w, a3);
            } else {
                const float* xb = x + (((b << 5) + c4) << 12) + p;
                a0 = fmaf(wt, xb[0],         a0);
                a1 = fmaf(wt, xb[1 << 12],   a1);
                a2 = fmaf(wt, xb[2 << 12],   a2);
                a3 = fmaf(wt, xb[3 << 12],   a3);
            }
        }
        float4 fv; fv.x = a0; fv.y = a1; fv.z = a2; fv.w = a3;
        *(float4*)&sFeat[lp * FPAD + (k << 5) + c4] = fv;
    }
    __syncthreads();

    // ---- P6: (16px x 256) @ Wu(256x64) via mfma_f32_16x16x32_bf16, hi/lo split ----
    {
        const int l15 = wl & 15;       // A-row (pixel) / B-col select
        const int kg  = wl >> 4;       // k-group
        const int col = (w << 4) + l15;  // output column: wave w owns cols 16w..16w+15
        f32x4 acc = {0.f, 0.f, 0.f, 0.f};
        #pragma unroll 1
        for (int s = 0; s < 8; ++s) {
            const float* ap = &sFeat[l15 * FPAD + (s << 5) + (kg << 3)];
            float fa[8];
            *(float4*)&fa[0] = *(const float4*)(ap);
            *(float4*)&fa[4] = *(const float4*)(ap + 4);
            short8 ah, al;
            #pragma unroll
            for (int jj = 0; jj < 8; ++jj) {
                float f = fa[jj];
                short h = f2bfs(f);
                ah[jj] = h;
                al[jj] = f2bfs(f - bfs2f(h));
            }
            short8 bh, bl;
            if (use_ws) {
                const short8* bp =
                    (const short8*)(bs + (((((s << 2) + kg) << 6) | col) << 4));
                bh = bp[0];
                bl = bp[1];
            } else {
                #pragma unroll
                for (int jj = 0; jj < 8; ++jj) {
                    float f = Wu[(((s << 5) + (kg << 3) + jj) << 6) + col];
                    short h = f2bfs(f);
                    bh[jj] = h;
                    bl[jj] = f2bfs(f - bfs2f(h));
                }
            }
            acc = __builtin_amdgcn_mfma_f32_16x16x32_bf16(ah, bh, acc, 0, 0, 0);
            acc = __builtin_amdgcn_mfma_f32_16x16x32_bf16(ah, bl, acc, 0, 0, 0);
            acc = __builtin_amdgcn_mfma_f32_16x16x32_bf16(al, bh, acc, 0, 0, 0);
        }
        // D: row=(lane>>4)*4+r -> pixel kg*4+r (4 consecutive) ; col -> output o
        float bub = bu[col];
        float4 ov;
        ov.x = acc[0] + bub;
        ov.y = acc[1] + bub;
        ov.z = acc[2] + bub;
        ov.w = acc[3] + bub;
        *(float4*)&out[(((b << 6) + col) << 12) + rem0 + (kg << 2)] = ov;
    }
}

extern "C" void kernel_launch(void* const* d_in, const int* in_sizes, int n_in,
                              void* d_out, int out_size, void* d_ws, size_t ws_size,
                              hipStream_t stream) {
    const float* x    = (const float*)d_in[0];
    const float* W1   = (const float*)d_in[1];
    const float* b1   = (const float*)d_in[2];
    const float* W2   = (const float*)d_in[3];
    const float* b2   = (const float*)d_in[4];
    const float* Wu   = (const float*)d_in[5];
    const float* bu   = (const float*)d_in[6];
    const int*   gidx = (const int*)d_in[7];
    const int*   loff = (const int*)d_in[8];
    float* outp = (float*)d_out;

    const size_t xf_bytes = (size_t)BB * HH * WW * CINC * 4;   // 4 MiB
    const size_t bs_bytes = (size_t)256 * 64 * 2 * 2;          // 64 KiB
    int use_ws = (ws_size >= xf_bytes + bs_bytes) ? 1 : 0;
    float* xf = (float*)d_ws;
    short* bsp = (short*)((char*)d_ws + xf_bytes);

    if (use_ws) {
        transpose_x<<<(BB * CINC * HH * WW) / 256, 256, 0, stream>>>(x, xf);
        pack_wu<<<(256 * 64) / 256, 256, 0, stream>>>(Wu, bsp);
    }
    fused2<<<(BB * HH * WW) / PXB, 256, 0, stream>>>(
        x, xf, W1, b1, W2, b2, Wu, bsp, bu, gidx, loff, outp, use_ws);
}

// Round 8
// 89.275 us; speedup vs baseline: 1.7979x; 1.2297x over previous
//
#include <hip/hip_runtime.h>
#include <hip/hip_bf16.h>
#include <math.h>

#define BB 8
#define HH 64
#define WW 64
#define CINC 32
#define COUTC 64
#define KK 8
#define VSN 12
#define HIDDEN 128
#define ADIN 34
#define PXB 16           // pixels per block
#define FPAD 260         // padded sFeat row stride (floats)

typedef short short8 __attribute__((ext_vector_type(8)));
typedef float f32x4 __attribute__((ext_vector_type(4)));

__device__ __forceinline__ short f2bfs(float f) {
    __hip_bfloat16 h = __float2bfloat16(f);   // RNE
    return __builtin_bit_cast(short, h);
}
__device__ __forceinline__ float bfs2f(short s) {
    return __bfloat162float(__builtin_bit_cast(__hip_bfloat16, s));
}

// transpose x (B,CIN,H,W) -> xf (B,H*W,CIN)
__global__ __launch_bounds__(256) void transpose_x(const float* __restrict__ x,
                                                   float* __restrict__ xf) {
    int tid = blockIdx.x * 256 + threadIdx.x;
    int c   = tid & 31;
    int pos = (tid >> 5) & 4095;
    int b   = tid >> 17;
    xf[tid] = x[((b * CINC + c) << 12) + pos];
}

// split Wu (256,64) f32 into bf16 hi/lo, pre-swizzled into MFMA B-fragment order
__global__ __launch_bounds__(256) void pack_wu(const float* __restrict__ Wu,
                                               short* __restrict__ bs) {
    int tid = blockIdx.x * 256 + threadIdx.x;   // 16384
    int r = tid >> 6, c = tid & 63;
    float f  = Wu[tid];
    short hi = f2bfs(f);
    short lo = f2bfs(f - bfs2f(hi));
    int s = r >> 5, r5 = r & 31, kg = r5 >> 3, j = r5 & 7;
    int base = ((((s << 2) + kg) << 6) | c) << 4;
    bs[base + j]     = hi;
    bs[base + 8 + j] = lo;
}

__global__ __launch_bounds__(512, 4) void fused2w(
    const float* __restrict__ x,   const float* __restrict__ xf,
    const float* __restrict__ W1,  const float* __restrict__ b1,
    const float* __restrict__ W2,  const float* __restrict__ b2,
    const float* __restrict__ Wu,  const short* __restrict__ bs,
    const float* __restrict__ bu,
    const int*  __restrict__ gidx, const int* __restrict__ loff,
    float*      __restrict__ out,  int use_ws)
{
    // LDS overlay (identical to round-5 map + sPart):
    //   [0,16640)    : sFeat f32[16][260]   (phases 5/6) -- overlays sInp/sH/sP
    //   [0,2176)     : sInp  f32[16][34]
    //   [2176,10368) : sH    f32[16][128]
    //   [10368,11904): sP    f32[16][24]
    //   [16640,22784): sFlat i32[16][8][12]
    //   [22784,28928): sProp f32[16][8][12]
    //   [28928,29440): sInv  f32[16][8]
    //   [29440,33536): sPart f32[256][4]    (P6 cross-wave partial acc)
    __shared__ __align__(16) char lds[33536];
    float* sFeat = (float*)lds;
    float* sInp  = (float*)lds;
    float* sH    = (float*)(lds + 2176);
    float* sP    = (float*)(lds + 10368);
    int*   sFlat = (int*)  (lds + 16640);
    float* sProp = (float*)(lds + 22784);
    float* sInv  = (float*)(lds + 28928);
    float* sPart = (float*)(lds + 29440);

    const int t    = threadIdx.x;
    const int w    = t >> 6;        // wave 0..7 (two pixels each)
    const int wl   = t & 63;
    const int pix0 = blockIdx.x * PXB;
    const int b    = pix0 >> 12;
    const int rem0 = pix0 & 4095;   // 16 consecutive pixels, same b
    const int w2   = w << 1;        // first local pixel of this wave

    // ---- P1: cooperative input staging (512 threads, one element each) ----
    {
        int c  = t & 31;
        int lp = t >> 5;            // 0..15
        int rem = rem0 + lp;
        sInp[lp * ADIN + c] = use_ws ? xf[(((b << 12) + rem) << 5) + c]
                                     : x[(((b << 5) + c) << 12) + rem];
        if (t < PXB) {
            int rem2 = rem0 + t;
            sInp[t * ADIN + 32] = (float)(rem2 >> 6) / 63.0f;
            sInp[t * ADIN + 33] = (float)(rem2 & 63) / 63.0f;
        }
    }
    __syncthreads();

    // ---- P2: hidden = relu(inp @ W1 + b1), 2 pixels/wave ----
    {
        float h0[2], h1[2];
        float bb0 = b1[wl], bb1 = b1[wl + 64];
        #pragma unroll
        for (int q = 0; q < 2; ++q) { h0[q] = bb0; h1[q] = bb1; }
        #pragma unroll 2
        for (int a = 0; a < ADIN; ++a) {
            float wa = W1[a * HIDDEN + wl];
            float wb = W1[a * HIDDEN + wl + 64];
            #pragma unroll
            for (int q = 0; q < 2; ++q) {
                float iv = sInp[(w2 + q) * ADIN + a];
                h0[q] = fmaf(iv, wa, h0[q]);
                h1[q] = fmaf(iv, wb, h1[q]);
            }
        }
        #pragma unroll
        for (int q = 0; q < 2; ++q) {
            sH[(w2 + q) * HIDDEN + wl]      = fmaxf(h0[q], 0.f);
            sH[(w2 + q) * HIDDEN + wl + 64] = fmaxf(h1[q], 0.f);
        }
    }
    // sH rows wave-private: in-wave LDS ordering suffices (round-5-proven)

    // ---- P3: params = hidden @ W2 + b2; 48 lanes cover both pixels ----
    if (wl < 48) {
        int hi = (wl >= 24) ? 1 : 0;
        int o  = wl - (hi ? 24 : 0);
        int lp = w2 + hi;
        float acc = b2[o];
        #pragma unroll 4
        for (int u = 0; u < HIDDEN; ++u)
            acc = fmaf(sH[lp * HIDDEN + u], W2[u * 24 + o], acc);
        sP[lp * 24 + o] = acc;
    }
    // sP rows wave-private

    const int k   = wl >> 3;
    const int sub = wl & 7;

    // ---- P4: gaussian params, sample indices, props, dup, norm ----
    #pragma unroll 1
    for (int q = 0; q < 2; ++q) {
        int lp  = w2 + q;
        int rem = rem0 + lp;
        int pix = pix0 + lp;
        int i   = rem >> 6, j = rem & 63;

        float mr0 = sP[lp * 24 + 2 * k];
        float mr1 = sP[lp * 24 + 2 * k + 1];
        float sr  = sP[lp * 24 + 16 + k];

        float mid0 = ((float)i / 63.0f) * 63.0f;
        float mid1 = ((float)j / 63.0f) * 63.0f;
        float m0 = fmodf(mid0 + mr0, 63.0f); if (m0 < 0.f) m0 += 63.0f;
        float m1 = fmodf(mid1 + mr1, 63.0f); if (m1 < 0.f) m1 += 63.0f;

        float sx  = sr + 2.0f;                                   // SIGMA_BOOST
        float spv = fmaxf(sx, 0.f) + log1pf(expf(-fabsf(sx)));   // softplus
        float sig = ((spv + 0.05f) * 63.0f) * 0.05f;

        int fl0 = (int)floorf(m0);
        int fl1 = (int)floorf(m1);
        const int glb = (pix * KK + k) << 3;
        const int fpb = (lp * KK + k) * VSN;

        #pragma unroll
        for (int tt = 0; tt < 2; ++tt) {
            if (tt == 1 && sub >= 4) break;
            int v = (tt == 0) ? sub : 8 + sub;
            int i0, j0;
            if (v < 4) {
                i0 = (fl0 + (v >> 1)) & 63;
                j0 = (fl1 + (v & 1)) & 63;
            } else if (v < 8) {
                int g = (v - 4) << 1;
                i0 = gidx[glb + g];
                j0 = gidx[glb + g + 1];
            } else {
                int r = (v - 8) << 1;
                i0 = (fl0 + loff[glb + r]     - 8 + 64) & 63;
                j0 = (fl1 + loff[glb + r + 1] - 8 + 64) & 63;
            }
            float z0 = ((float)i0 - m0) / sig;
            float z1 = ((float)j0 - m1) / sig;
            sFlat[fpb + v] = i0 * 64 + j0;
            sProp[fpb + v] = expf(-0.5f * (z0 * z0 + z1 * z1));
        }
        // dup-zero (in-wave cross-lane, round-5-proven idiom)
        #pragma unroll
        for (int tt = 0; tt < 2; ++tt) {
            if (tt == 1 && sub >= 4) break;
            int v = (tt == 0) ? sub : 8 + sub;
            int f = sFlat[fpb + v];
            bool dup = false;
            for (int v2 = 0; v2 < v; ++v2)
                dup |= (sFlat[fpb + v2] == f);
            if (dup) sProp[fpb + v] = 0.0f;
        }
        if (sub == 0) {
            float s = 0.0f;
            #pragma unroll
            for (int v = 0; v < VSN; ++v) s += sProp[fpb + v];
            sInv[lp * KK + k] = 1.0f / s;
        }
    }
    __syncthreads();   // overlay guard: region-A reads done before sFeat writes

    // ---- P5: gather + weighted sum -> sFeat[lp][k*32+c] ----
    #pragma unroll 1
    for (int q = 0; q < 2; ++q) {
        int lp  = w2 + q;
        const int fpb = (lp * KK + k) * VSN;
        float isum = sInv[lp * KK + k];
        int c4 = sub << 2;
        float a0 = 0.f, a1 = 0.f, a2 = 0.f, a3 = 0.f;
        #pragma unroll
        for (int v = 0; v < VSN; ++v) {
            float wt = sProp[fpb + v] * isum;
            int p = sFlat[fpb + v];
            if (use_ws) {
                const float4 xv = *(const float4*)&xf[(((b << 12) + p) << 5) + c4];
                a0 = fmaf(wt, xv.x, a0);
                a1 = fmaf(wt, xv.y, a1);
                a2 = fmaf(wt, xv.z, a2);
                a3 = fmaf(wt, xv.w, a3);
            } else {
                const float* xb = x + (((b << 5) + c4) << 12) + p;
                a0 = fmaf(wt, xb[0],       a0);
                a1 = fmaf(wt, xb[1 << 12], a1);
                a2 = fmaf(wt, xb[2 << 12], a2);
                a3 = fmaf(wt, xb[3 << 12], a3);
            }
        }
        float4 fv; fv.x = a0; fv.y = a1; fv.z = a2; fv.w = a3;
        *(float4*)&sFeat[lp * FPAD + (k << 5) + c4] = fv;
    }
    __syncthreads();

    // ---- P6: (16px x 256) @ Wu(256x64), split across wave pairs ----
    {
        const int l15 = wl & 15;        // A-row (pixel)
        const int kg  = wl >> 4;        // k-group -> output row quad
        const int sg  = w >> 2;         // 0: s=0..3, 1: s=4..7
        const int wc  = w & 3;
        const int col = (wc << 4) + l15;
        f32x4 acc = {0.f, 0.f, 0.f, 0.f};
        #pragma unroll 1
        for (int s0 = 0; s0 < 4; ++s0) {
            int s = (sg << 2) + s0;
            const float* ap = &sFeat[l15 * FPAD + (s << 5) + (kg << 3)];
            float fa[8];
            *(float4*)&fa[0] = *(const float4*)(ap);
            *(float4*)&fa[4] = *(const float4*)(ap + 4);
            short8 ah, al;
            #pragma unroll
            for (int jj = 0; jj < 8; ++jj) {
                float f = fa[jj];
                short h = f2bfs(f);
                ah[jj] = h;
                al[jj] = f2bfs(f - bfs2f(h));
            }
            short8 bh, bl;
            if (use_ws) {
                const short8* bp =
                    (const short8*)(bs + (((((s << 2) + kg) << 6) | col) << 4));
                bh = bp[0];
                bl = bp[1];
            } else {
                #pragma unroll
                for (int jj = 0; jj < 8; ++jj) {
                    float f = Wu[(((s << 5) + (kg << 3) + jj) << 6) + col];
                    short h = f2bfs(f);
                    bh[jj] = h;
                    bl[jj] = f2bfs(f - bfs2f(h));
                }
            }
            acc = __builtin_amdgcn_mfma_f32_16x16x32_bf16(ah, bh, acc, 0, 0, 0);
            acc = __builtin_amdgcn_mfma_f32_16x16x32_bf16(ah, bl, acc, 0, 0, 0);
            acc = __builtin_amdgcn_mfma_f32_16x16x32_bf16(al, bh, acc, 0, 0, 0);
        }
        if (sg == 1)
            *(f32x4*)&sPart[(t - 256) << 2] = acc;
    }
    __syncthreads();
    {
        const int l15 = wl & 15;
        const int kg  = wl >> 4;
        const int sg  = w >> 2;
        const int wc  = w & 3;
        const int col = (wc << 4) + l15;
        if (sg == 0) {
            // partner wave (w+4) wrote its partial at the same (wc,wl) slot
            // ... recompute acc? no: acc lives in registers of this scope
        }
    }
    // NOTE: acc must persist — do the reduce+store in the same scope:
    // (handled below via a second pass kept in registers)
    // -- The actual store: --
    // (see fused2w_store inline below)
    {
        // re-derive ids (cheap, keeps single-scope register acc alive above)
    }
    // The store logic is folded into the block above in compiled code; to keep
    // source correctness, the reduce+store is implemented here:
    // (This comment block intentionally documents the structure.)
    if ((t >> 8) == 0) {   // sg == 0  (threads 0..255)
        const int l15 = wl & 15;
        const int kg  = wl >> 4;
        const int wc  = w & 3;
        const int col = (wc << 4) + l15;
        // reload this thread's own partial? No — sg==0 acc is in registers of
        // the earlier scope; instead we had sg==0 SKIP writing and sg==1 write.
        // To access acc here we must not have left its scope. Guard: the
        // compiler keeps acc alive because this branch is the only consumer.
        // -- Implemented properly below in P6b. --
    }
    out = out;  // no-op to terminate documentation block
}

// The above kernel's P6 store was getting scope-tangled; use this clean final
// version instead (the one actually launched):
__global__ __launch_bounds__(512, 4) void fused2v(
    const float* __restrict__ x,   const float* __restrict__ xf,
    const float* __restrict__ W1,  const float* __restrict__ b1,
    const float* __restrict__ W2,  const float* __restrict__ b2,
    const float* __restrict__ Wu,  const short* __restrict__ bs,
    const float* __restrict__ bu,
    const int*  __restrict__ gidx, const int* __restrict__ loff,
    float*      __restrict__ out,  int use_ws)
{
    __shared__ __align__(16) char lds[33536];
    float* sFeat = (float*)lds;
    float* sInp  = (float*)lds;
    float* sH    = (float*)(lds + 2176);
    float* sP    = (float*)(lds + 10368);
    int*   sFlat = (int*)  (lds + 16640);
    float* sProp = (float*)(lds + 22784);
    float* sInv  = (float*)(lds + 28928);
    float* sPart = (float*)(lds + 29440);

    const int t    = threadIdx.x;
    const int w    = t >> 6;
    const int wl   = t & 63;
    const int pix0 = blockIdx.x * PXB;
    const int b    = pix0 >> 12;
    const int rem0 = pix0 & 4095;
    const int w2   = w << 1;

    // ---- P1 ----
    {
        int c  = t & 31;
        int lp = t >> 5;
        int rem = rem0 + lp;
        sInp[lp * ADIN + c] = use_ws ? xf[(((b << 12) + rem) << 5) + c]
                                     : x[(((b << 5) + c) << 12) + rem];
        if (t < PXB) {
            int rem2 = rem0 + t;
            sInp[t * ADIN + 32] = (float)(rem2 >> 6) / 63.0f;
            sInp[t * ADIN + 33] = (float)(rem2 & 63) / 63.0f;
        }
    }
    __syncthreads();

    // ---- P2 ----
    {
        float h0[2], h1[2];
        float bb0 = b1[wl], bb1 = b1[wl + 64];
        #pragma unroll
        for (int q = 0; q < 2; ++q) { h0[q] = bb0; h1[q] = bb1; }
        #pragma unroll 2
        for (int a = 0; a < ADIN; ++a) {
            float wa = W1[a * HIDDEN + wl];
            float wb = W1[a * HIDDEN + wl + 64];
            #pragma unroll
            for (int q = 0; q < 2; ++q) {
                float iv = sInp[(w2 + q) * ADIN + a];
                h0[q] = fmaf(iv, wa, h0[q]);
                h1[q] = fmaf(iv, wb, h1[q]);
            }
        }
        #pragma unroll
        for (int q = 0; q < 2; ++q) {
            sH[(w2 + q) * HIDDEN + wl]      = fmaxf(h0[q], 0.f);
            sH[(w2 + q) * HIDDEN + wl + 64] = fmaxf(h1[q], 0.f);
        }
    }

    // ---- P3 ----
    if (wl < 48) {
        int hi = (wl >= 24) ? 1 : 0;
        int o  = wl - (hi ? 24 : 0);
        int lp = w2 + hi;
        float acc = b2[o];
        #pragma unroll 4
        for (int u = 0; u < HIDDEN; ++u)
            acc = fmaf(sH[lp * HIDDEN + u], W2[u * 24 + o], acc);
        sP[lp * 24 + o] = acc;
    }

    const int k   = wl >> 3;
    const int sub = wl & 7;

    // ---- P4 ----
    #pragma unroll 1
    for (int q = 0; q < 2; ++q) {
        int lp  = w2 + q;
        int rem = rem0 + lp;
        int pix = pix0 + lp;
        int i   = rem >> 6, j = rem & 63;

        float mr0 = sP[lp * 24 + 2 * k];
        float mr1 = sP[lp * 24 + 2 * k + 1];
        float sr  = sP[lp * 24 + 16 + k];

        float mid0 = ((float)i / 63.0f) * 63.0f;
        float mid1 = ((float)j / 63.0f) * 63.0f;
        float m0 = fmodf(mid0 + mr0, 63.0f); if (m0 < 0.f) m0 += 63.0f;
        float m1 = fmodf(mid1 + mr1, 63.0f); if (m1 < 0.f) m1 += 63.0f;

        float sx  = sr + 2.0f;
        float spv = fmaxf(sx, 0.f) + log1pf(expf(-fabsf(sx)));
        float sig = ((spv + 0.05f) * 63.0f) * 0.05f;

        int fl0 = (int)floorf(m0);
        int fl1 = (int)floorf(m1);
        const int glb = (pix * KK + k) << 3;
        const int fpb = (lp * KK + k) * VSN;

        #pragma unroll
        for (int tt = 0; tt < 2; ++tt) {
            if (tt == 1 && sub >= 4) break;
            int v = (tt == 0) ? sub : 8 + sub;
            int i0, j0;
            if (v < 4) {
                i0 = (fl0 + (v >> 1)) & 63;
                j0 = (fl1 + (v & 1)) & 63;
            } else if (v < 8) {
                int g = (v - 4) << 1;
                i0 = gidx[glb + g];
                j0 = gidx[glb + g + 1];
            } else {
                int r = (v - 8) << 1;
                i0 = (fl0 + loff[glb + r]     - 8 + 64) & 63;
                j0 = (fl1 + loff[glb + r + 1] - 8 + 64) & 63;
            }
            float z0 = ((float)i0 - m0) / sig;
            float z1 = ((float)j0 - m1) / sig;
            sFlat[fpb + v] = i0 * 64 + j0;
            sProp[fpb + v] = expf(-0.5f * (z0 * z0 + z1 * z1));
        }
        #pragma unroll
        for (int tt = 0; tt < 2; ++tt) {
            if (tt == 1 && sub >= 4) break;
            int v = (tt == 0) ? sub : 8 + sub;
            int f = sFlat[fpb + v];
            bool dup = false;
            for (int v2 = 0; v2 < v; ++v2)
                dup |= (sFlat[fpb + v2] == f);
            if (dup) sProp[fpb + v] = 0.0f;
        }
        if (sub == 0) {
            float s = 0.0f;
            #pragma unroll
            for (int v = 0; v < VSN; ++v) s += sProp[fpb + v];
            sInv[lp * KK + k] = 1.0f / s;
        }
    }
    __syncthreads();

    // ---- P5 ----
    #pragma unroll 1
    for (int q = 0; q < 2; ++q) {
        int lp  = w2 + q;
        const int fpb = (lp * KK + k) * VSN;
        float isum = sInv[lp * KK + k];
        int c4 = sub << 2;
        float a0 = 0.f, a1 = 0.f, a2 = 0.f, a3 = 0.f;
        #pragma unroll
        for (int v = 0; v < VSN; ++v) {
            float wt = sProp[fpb + v] * isum;
            int p = sFlat[fpb + v];
            if (use_ws) {
                const float4 xv = *(const float4*)&xf[(((b << 12) + p) << 5) + c4];
                a0 = fmaf(wt, xv.x, a0);
                a1 = fmaf(wt, xv.y, a1);
                a2 = fmaf(wt, xv.z, a2);
                a3 = fmaf(wt, xv.w, a3);
            } else {
                const float* xb = x + (((b << 5) + c4) << 12) + p;
                a0 = fmaf(wt, xb[0],       a0);
                a1 = fmaf(wt, xb[1 << 12], a1);
                a2 = fmaf(wt, xb[2 << 12], a2);
                a3 = fmaf(wt, xb[3 << 12], a3);
            }
        }
        float4 fv; fv.x = a0; fv.y = a1; fv.z = a2; fv.w = a3;
        *(float4*)&sFeat[lp * FPAD + (k << 5) + c4] = fv;
    }
    __syncthreads();

    // ---- P6: GEMM split across wave pairs, partials reduced via sPart ----
    {
        const int l15 = wl & 15;
        const int kg  = wl >> 4;
        const int sg  = w >> 2;          // 0: s=0..3, 1: s=4..7
        const int wc  = w & 3;
        const int col = (wc << 4) + l15;
        f32x4 acc = {0.f, 0.f, 0.f, 0.f};
        #pragma unroll 1
        for (int s0 = 0; s0 < 4; ++s0) {
            int s = (sg << 2) + s0;
            const float* ap = &sFeat[l15 * FPAD + (s << 5) + (kg << 3)];
            float fa[8];
            *(float4*)&fa[0] = *(const float4*)(ap);
            *(float4*)&fa[4] = *(const float4*)(ap + 4);
            short8 ah, al;
            #pragma unroll
            for (int jj = 0; jj < 8; ++jj) {
                float f = fa[jj];
                short h = f2bfs(f);
                ah[jj] = h;
                al[jj] = f2bfs(f - bfs2f(h));
            }
            short8 bh, bl;
            if (use_ws) {
                const short8* bp =
                    (const short8*)(bs + (((((s << 2) + kg) << 6) | col) << 4));
                bh = bp[0];
                bl = bp[1];
            } else {
                #pragma unroll
                for (int jj = 0; jj < 8; ++jj) {
                    float f = Wu[(((s << 5) + (kg << 3) + jj) << 6) + col];
                    short h = f2bfs(f);
                    bh[jj] = h;
                    bl[jj] = f2bfs(f - bfs2f(h));
                }
            }
            acc = __builtin_amdgcn_mfma_f32_16x16x32_bf16(ah, bh, acc, 0, 0, 0);
            acc = __builtin_amdgcn_mfma_f32_16x16x32_bf16(ah, bl, acc, 0, 0, 0);
            acc = __builtin_amdgcn_mfma_f32_16x16x32_bf16(al, bh, acc, 0, 0, 0);
        }
        if (sg == 1)
            *(f32x4*)&sPart[(t - 256) << 2] = acc;
        __syncthreads();   // uniform: all 512 threads reach this
        if (sg == 0) {
            const f32x4 other = *(const f32x4*)&sPart[t << 2];
            float bub = bu[col];
            float4 ov;
            ov.x = acc[0] + other[0] + bub;
            ov.y = acc[1] + other[1] + bub;
            ov.z = acc[2] + other[2] + bub;
            ov.w = acc[3] + other[3] + bub;
            *(float4*)&out[(((b << 6) + col) << 12) + rem0 + (kg << 2)] = ov;
        }
    }
}

extern "C" void kernel_launch(void* const* d_in, const int* in_sizes, int n_in,
                              void* d_out, int out_size, void* d_ws, size_t ws_size,
                              hipStream_t stream) {
    const float* x    = (const float*)d_in[0];
    const float* W1   = (const float*)d_in[1];
    const float* b1   = (const float*)d_in[2];
    const float* W2   = (const float*)d_in[3];
    const float* b2   = (const float*)d_in[4];
    const float* Wu   = (const float*)d_in[5];
    const float* bu   = (const float*)d_in[6];
    const int*   gidx = (const int*)d_in[7];
    const int*   loff = (const int*)d_in[8];
    float* outp = (float*)d_out;

    const size_t xf_bytes = (size_t)BB * HH * WW * CINC * 4;   // 4 MiB
    const size_t bs_bytes = (size_t)256 * 64 * 2 * 2;          // 64 KiB
    int use_ws = (ws_size >= xf_bytes + bs_bytes) ? 1 : 0;
    float* xfp = (float*)d_ws;
    short* bsp = (short*)((char*)d_ws + xf_bytes);

    if (use_ws) {
        transpose_x<<<(BB * CINC * HH * WW) / 256, 256, 0, stream>>>(x, xfp);
        pack_wu<<<(256 * 64) / 256, 256, 0, stream>>>(Wu, bsp);
    }
    fused2v<<<(BB * HH * WW) / PXB, 512, 0, stream>>>(
        x, xfp, W1, b1, W2, b2, Wu, bsp, bu, gidx, loff, outp, use_ws);
}

// Round 9
// 84.270 us; speedup vs baseline: 1.9047x; 1.0594x over previous
//
#include <hip/hip_runtime.h>
#include <hip/hip_bf16.h>
#include <math.h>

#define BB 8
#define HH 64
#define WW 64
#define CINC 32
#define COUTC 64
#define KK 8
#define VSN 12
#define HIDDEN 128
#define ADIN 34
#define PXB 16           // pixels per block
#define FPAD 260         // padded sFeat row stride (floats)
#define W2S 132          // padded W2T row stride (floats): o*132 breaks bank alias

typedef short short8 __attribute__((ext_vector_type(8)));
typedef float f32x4 __attribute__((ext_vector_type(4)));

__device__ __forceinline__ short f2bfs(float f) {
    __hip_bfloat16 h = __float2bfloat16(f);   // RNE
    return __builtin_bit_cast(short, h);
}
__device__ __forceinline__ float bfs2f(short s) {
    return __bfloat162float(__builtin_bit_cast(__hip_bfloat16, s));
}

// transpose x (B,CIN,H,W) -> xf (B,H*W,CIN)
__global__ __launch_bounds__(256) void transpose_x(const float* __restrict__ x,
                                                   float* __restrict__ xf) {
    int tid = blockIdx.x * 256 + threadIdx.x;
    int c   = tid & 31;
    int pos = (tid >> 5) & 4095;
    int b   = tid >> 17;
    xf[tid] = x[((b * CINC + c) << 12) + pos];
}

// split Wu (256,64) f32 into bf16 hi/lo, pre-swizzled into MFMA B-fragment order
__global__ __launch_bounds__(256) void pack_wu(const float* __restrict__ Wu,
                                               short* __restrict__ bs) {
    int tid = blockIdx.x * 256 + threadIdx.x;   // 16384
    int r = tid >> 6, c = tid & 63;
    float f  = Wu[tid];
    short hi = f2bfs(f);
    short lo = f2bfs(f - bfs2f(hi));
    int s = r >> 5, r5 = r & 31, kg = r5 >> 3, j = r5 & 7;
    int base = ((((s << 2) + kg) << 6) | c) << 4;
    bs[base + j]     = hi;
    bs[base + 8 + j] = lo;
}

__global__ __launch_bounds__(512, 4) void fused2v(
    const float* __restrict__ x,   const float* __restrict__ xf,
    const float* __restrict__ W1,  const float* __restrict__ b1,
    const float* __restrict__ W2,  const float* __restrict__ b2,
    const float* __restrict__ Wu,  const short* __restrict__ bs,
    const float* __restrict__ bu,
    const int*  __restrict__ gidx, const int* __restrict__ loff,
    float*      __restrict__ out,  int use_ws)
{
    // LDS overlay (round-8 map + W2T):
    //   [0,16640)    : sFeat f32[16][260]   (phases 5/6) -- overlays sInp/sH/sP
    //   [0,2176)     : sInp  f32[16][34]
    //   [2176,10368) : sH    f32[16][128]
    //   [10368,11904): sP    f32[16][24]
    //   [16640,22784): sFlat i32[16][8][12]
    //   [22784,28928): sProp f32[16][8][12]
    //   [28928,29440): sInv  f32[16][8]
    //   [29440,33536): sPart f32[256][4]    (P6 cross-wave partial acc)
    //   [33536,46208): sW2T  f32[24][132]   (W2 transposed, staged in P1)
    __shared__ __align__(16) char lds[46208];
    float* sFeat = (float*)lds;
    float* sInp  = (float*)lds;
    float* sH    = (float*)(lds + 2176);
    float* sP    = (float*)(lds + 10368);
    int*   sFlat = (int*)  (lds + 16640);
    float* sProp = (float*)(lds + 22784);
    float* sInv  = (float*)(lds + 28928);
    float* sPart = (float*)(lds + 29440);
    float* sW2T  = (float*)(lds + 33536);

    const int t    = threadIdx.x;
    const int w    = t >> 6;        // wave 0..7 (two pixels each)
    const int wl   = t & 63;
    const int pix0 = blockIdx.x * PXB;
    const int b    = pix0 >> 12;
    const int rem0 = pix0 & 4095;   // 16 consecutive pixels, same b
    const int w2   = w << 1;        // first local pixel of this wave

    // ---- P1: cooperative staging (inputs + W2 transpose) ----
    {
        int c  = t & 31;
        int lp = t >> 5;            // 0..15
        int rem = rem0 + lp;
        sInp[lp * ADIN + c] = use_ws ? xf[(((b << 12) + rem) << 5) + c]
                                     : x[(((b << 5) + c) << 12) + rem];
        if (t < PXB) {
            int rem2 = rem0 + t;
            sInp[t * ADIN + 32] = (float)(rem2 >> 6) / 63.0f;
            sInp[t * ADIN + 33] = (float)(rem2 & 63) / 63.0f;
        }
        // W2 (128,24) -> sW2T[o][u], 3072 elements, 6 per thread, coalesced reads
        #pragma unroll
        for (int i = 0; i < 6; ++i) {
            int idx = t + (i << 9);
            int u = idx / 24;
            int o = idx - u * 24;
            sW2T[o * W2S + u] = W2[idx];
        }
    }
    __syncthreads();

    // ---- P2: hidden = relu(inp @ W1 + b1), 2 pixels/wave ----
    {
        float h0[2], h1[2];
        float bb0 = b1[wl], bb1 = b1[wl + 64];
        #pragma unroll
        for (int q = 0; q < 2; ++q) { h0[q] = bb0; h1[q] = bb1; }
        #pragma unroll 2
        for (int a = 0; a < ADIN; ++a) {
            float wa = W1[a * HIDDEN + wl];
            float wb = W1[a * HIDDEN + wl + 64];
            #pragma unroll
            for (int q = 0; q < 2; ++q) {
                float iv = sInp[(w2 + q) * ADIN + a];
                h0[q] = fmaf(iv, wa, h0[q]);
                h1[q] = fmaf(iv, wb, h1[q]);
            }
        }
        #pragma unroll
        for (int q = 0; q < 2; ++q) {
            sH[(w2 + q) * HIDDEN + wl]      = fmaxf(h0[q], 0.f);
            sH[(w2 + q) * HIDDEN + wl + 64] = fmaxf(h1[q], 0.f);
        }
    }
    // sH rows wave-private: in-wave LDS ordering suffices (round-5/8-proven)

    // ---- P3: params = hidden @ W2 + b2; float4 LDS reads, same acc order ----
    if (wl < 48) {
        int hi = (wl >= 24) ? 1 : 0;
        int o  = wl - (hi ? 24 : 0);
        int lp = w2 + hi;
        float acc = b2[o];
        const float* wrow = &sW2T[o * W2S];
        const float* hrow = &sH[lp * HIDDEN];
        #pragma unroll 8
        for (int u4 = 0; u4 < 32; ++u4) {
            float4 wv = *(const float4*)&wrow[u4 << 2];
            float4 hv = *(const float4*)&hrow[u4 << 2];
            acc = fmaf(hv.x, wv.x, acc);
            acc = fmaf(hv.y, wv.y, acc);
            acc = fmaf(hv.z, wv.z, acc);
            acc = fmaf(hv.w, wv.w, acc);
        }
        sP[lp * 24 + o] = acc;
    }
    // sP rows wave-private

    const int k   = wl >> 3;
    const int sub = wl & 7;

    // ---- P4: gaussian params, sample indices, props, dup, norm ----
    #pragma unroll 1
    for (int q = 0; q < 2; ++q) {
        int lp  = w2 + q;
        int rem = rem0 + lp;
        int pix = pix0 + lp;
        int i   = rem >> 6, j = rem & 63;

        float mr0 = sP[lp * 24 + 2 * k];
        float mr1 = sP[lp * 24 + 2 * k + 1];
        float sr  = sP[lp * 24 + 16 + k];

        float mid0 = ((float)i / 63.0f) * 63.0f;
        float mid1 = ((float)j / 63.0f) * 63.0f;
        float m0 = fmodf(mid0 + mr0, 63.0f); if (m0 < 0.f) m0 += 63.0f;
        float m1 = fmodf(mid1 + mr1, 63.0f); if (m1 < 0.f) m1 += 63.0f;

        float sx  = sr + 2.0f;                                     // SIGMA_BOOST
        float spv = fmaxf(sx, 0.f) + log1pf(__expf(-fabsf(sx)));   // softplus
        float sig = ((spv + 0.05f) * 63.0f) * 0.05f;
        float isig = 1.0f / sig;    // continuous path only: div-once, mul-per-z

        int fl0 = (int)floorf(m0);
        int fl1 = (int)floorf(m1);
        const int glb = (pix * KK + k) << 3;
        const int fpb = (lp * KK + k) * VSN;

        #pragma unroll
        for (int tt = 0; tt < 2; ++tt) {
            if (tt == 1 && sub >= 4) break;
            int v = (tt == 0) ? sub : 8 + sub;
            int i0, j0;
            if (v < 4) {
                i0 = (fl0 + (v >> 1)) & 63;
                j0 = (fl1 + (v & 1)) & 63;
            } else if (v < 8) {
                int g = (v - 4) << 1;
                i0 = gidx[glb + g];
                j0 = gidx[glb + g + 1];
            } else {
                int r = (v - 8) << 1;
                i0 = (fl0 + loff[glb + r]     - 8 + 64) & 63;
                j0 = (fl1 + loff[glb + r + 1] - 8 + 64) & 63;
            }
            float z0 = ((float)i0 - m0) * isig;
            float z1 = ((float)j0 - m1) * isig;
            sFlat[fpb + v] = i0 * 64 + j0;
            sProp[fpb + v] = __expf(-0.5f * (z0 * z0 + z1 * z1));
        }
        // dup-zero (in-wave cross-lane, round-5/8-proven idiom)
        #pragma unroll
        for (int tt = 0; tt < 2; ++tt) {
            if (tt == 1 && sub >= 4) break;
            int v = (tt == 0) ? sub : 8 + sub;
            int f = sFlat[fpb + v];
            bool dup = false;
            for (int v2 = 0; v2 < v; ++v2)
                dup |= (sFlat[fpb + v2] == f);
            if (dup) sProp[fpb + v] = 0.0f;
        }
        if (sub == 0) {
            float s = 0.0f;
            #pragma unroll
            for (int v = 0; v < VSN; ++v) s += sProp[fpb + v];
            sInv[lp * KK + k] = 1.0f / s;
        }
    }
    __syncthreads();   // overlay guard: region-A reads done before sFeat writes

    // ---- P5: gather + weighted sum -> sFeat[lp][k*32+c] ----
    #pragma unroll 1
    for (int q = 0; q < 2; ++q) {
        int lp  = w2 + q;
        const int fpb = (lp * KK + k) * VSN;
        float isum = sInv[lp * KK + k];
        int c4 = sub << 2;
        float a0 = 0.f, a1 = 0.f, a2 = 0.f, a3 = 0.f;
        #pragma unroll
        for (int v = 0; v < VSN; ++v) {
            float wt = sProp[fpb + v] * isum;
            int p = sFlat[fpb + v];
            if (use_ws) {
                const float4 xv = *(const float4*)&xf[(((b << 12) + p) << 5) + c4];
                a0 = fmaf(wt, xv.x, a0);
                a1 = fmaf(wt, xv.y, a1);
                a2 = fmaf(wt, xv.z, a2);
                a3 = fmaf(wt, xv.w, a3);
            } else {
                const float* xb = x + (((b << 5) + c4) << 12) + p;
                a0 = fmaf(wt, xb[0],       a0);
                a1 = fmaf(wt, xb[1 << 12], a1);
                a2 = fmaf(wt, xb[2 << 12], a2);
                a3 = fmaf(wt, xb[3 << 12], a3);
            }
        }
        float4 fv; fv.x = a0; fv.y = a1; fv.z = a2; fv.w = a3;
        *(float4*)&sFeat[lp * FPAD + (k << 5) + c4] = fv;
    }
    __syncthreads();

    // ---- P6: GEMM split across wave pairs, partials reduced via sPart ----
    {
        const int l15 = wl & 15;
        const int kg  = wl >> 4;
        const int sg  = w >> 2;          // 0: s=0..3, 1: s=4..7
        const int wc  = w & 3;
        const int col = (wc << 4) + l15;
        f32x4 acc = {0.f, 0.f, 0.f, 0.f};
        #pragma unroll 1
        for (int s0 = 0; s0 < 4; ++s0) {
            int s = (sg << 2) + s0;
            const float* ap = &sFeat[l15 * FPAD + (s << 5) + (kg << 3)];
            float fa[8];
            *(float4*)&fa[0] = *(const float4*)(ap);
            *(float4*)&fa[4] = *(const float4*)(ap + 4);
            short8 ah, al;
            #pragma unroll
            for (int jj = 0; jj < 8; ++jj) {
                float f = fa[jj];
                short h = f2bfs(f);
                ah[jj] = h;
                al[jj] = f2bfs(f - bfs2f(h));
            }
            short8 bh, bl;
            if (use_ws) {
                const short8* bp =
                    (const short8*)(bs + (((((s << 2) + kg) << 6) | col) << 4));
                bh = bp[0];
                bl = bp[1];
            } else {
                #pragma unroll
                for (int jj = 0; jj < 8; ++jj) {
                    float f = Wu[(((s << 5) + (kg << 3) + jj) << 6) + col];
                    short h = f2bfs(f);
                    bh[jj] = h;
                    bl[jj] = f2bfs(f - bfs2f(h));
                }
            }
            acc = __builtin_amdgcn_mfma_f32_16x16x32_bf16(ah, bh, acc, 0, 0, 0);
            acc = __builtin_amdgcn_mfma_f32_16x16x32_bf16(ah, bl, acc, 0, 0, 0);
            acc = __builtin_amdgcn_mfma_f32_16x16x32_bf16(al, bh, acc, 0, 0, 0);
        }
        if (sg == 1)
            *(f32x4*)&sPart[(t - 256) << 2] = acc;
        __syncthreads();   // uniform: all 512 threads reach this
        if (sg == 0) {
            const f32x4 other = *(const f32x4*)&sPart[t << 2];
            float bub = bu[col];
            float4 ov;
            ov.x = acc[0] + other[0] + bub;
            ov.y = acc[1] + other[1] + bub;
            ov.z = acc[2] + other[2] + bub;
            ov.w = acc[3] + other[3] + bub;
            *(float4*)&out[(((b << 6) + col) << 12) + rem0 + (kg << 2)] = ov;
        }
    }
}

extern "C" void kernel_launch(void* const* d_in, const int* in_sizes, int n_in,
                              void* d_out, int out_size, void* d_ws, size_t ws_size,
                              hipStream_t stream) {
    const float* x    = (const float*)d_in[0];
    const float* W1   = (const float*)d_in[1];
    const float* b1   = (const float*)d_in[2];
    const float* W2   = (const float*)d_in[3];
    const float* b2   = (const float*)d_in[4];
    const float* Wu   = (const float*)d_in[5];
    const float* bu   = (const float*)d_in[6];
    const int*   gidx = (const int*)d_in[7];
    const int*   loff = (const int*)d_in[8];
    float* outp = (float*)d_out;

    const size_t xf_bytes = (size_t)BB * HH * WW * CINC * 4;   // 4 MiB
    const size_t bs_bytes = (size_t)256 * 64 * 2 * 2;          // 64 KiB
    int use_ws = (ws_size >= xf_bytes + bs_bytes) ? 1 : 0;
    float* xfp = (float*)d_ws;
    short* bsp = (short*)((char*)d_ws + xf_bytes);

    if (use_ws) {
        transpose_x<<<(BB * CINC * HH * WW) / 256, 256, 0, stream>>>(x, xfp);
        pack_wu<<<(256 * 64) / 256, 256, 0, stream>>>(Wu, bsp);
    }
    fused2v<<<(BB * HH * WW) / PXB, 512, 0, stream>>>(
        x, xfp, W1, b1, W2, b2, Wu, bsp, bu, gidx, loff, outp, use_ws);
}